// Round 13
// baseline (304.977 us; speedup 1.0000x reference)
//
#include <hip/hip_runtime.h>
#include <hip/hip_fp16.h>
#include <stdint.h>

// ---------------------------------------------------------------------------
// GCN 3-layer forward, MI355X. Round 13:
//  - ALL dropout threefry moved into k_scale_mask (was k_scale16): memory-bound
//    wave-per-row kernel absorbs 6 ballots/node in its idle VALU slots.
//    k_agg_x is now a pure gather; k_agg_w applies mask2 bits (r10 epilogue).
//    (r10 showed dedicated-kernel PRNG = serial VALU time; r11/r12 showed
//     inline-in-agg PRNG pushes agg VALUBusy to 67%. This hides it properly.)
//  - GEMMs / CSR / graph structure unchanged from r12 (13 nodes).
// Pipeline:
//   CSR; xs16=f16(x*dinv) + mask1/mask2 ballots; ag=dt*sum xs16 (f16 hi/lo');
//   h1=relu(drop1(ag@W1+b1)) f16 (mask1 bits); hw2=f16((h1@W2)*dinv);
//   h2=relu(drop2(dt*sum hw2+b2)) (mask2 bits); out=h2@W3+b3 (fp32).
// ---------------------------------------------------------------------------

typedef __attribute__((ext_vector_type(8))) short s8v;   // 8 f16 (4 VGPR)
typedef __attribute__((ext_vector_type(4))) float f4v;   // 4 f32 acc

__device__ __host__ __forceinline__ uint32_t tf_rotl(uint32_t v, int r) {
  return (v << r) | (v >> (32 - r));
}

__device__ __host__ __forceinline__ void threefry2x32(uint32_t k0, uint32_t k1,
                                                      uint32_t x0, uint32_t x1,
                                                      uint32_t& o0, uint32_t& o1) {
  const uint32_t k2 = k0 ^ k1 ^ 0x1BD11BDAu;
  x0 += k0; x1 += k1;
#define TFR(r) { x0 += x1; x1 = tf_rotl(x1, r); x1 ^= x0; }
  TFR(13) TFR(15) TFR(26) TFR(6)
  x0 += k1; x1 += k2 + 1u;
  TFR(17) TFR(29) TFR(16) TFR(24)
  x0 += k2; x1 += k0 + 2u;
  TFR(13) TFR(15) TFR(26) TFR(6)
  x0 += k0; x1 += k1 + 3u;
  TFR(17) TFR(29) TFR(16) TFR(24)
  x0 += k1; x1 += k2 + 4u;
  TFR(13) TFR(15) TFR(26) TFR(6)
  x0 += k2; x1 += k0 + 5u;
#undef TFR
  o0 = x0; o1 = x1;
}

__device__ __forceinline__ bool drop_keep(uint32_t k0, uint32_t k1, uint32_t j) {
  uint32_t a, b;
  threefry2x32(k0, k1, 0u, j, a, b);
  uint32_t bits = a ^ b;
  float u = __uint_as_float((bits >> 9) | 0x3f800000u) - 1.0f;
  return u < 0.8f;
}

// f16 hi / scaled-lo helpers (lo pre-scaled by 2048 to stay in normal range)
__device__ __forceinline__ void split16(float v, uint16_t& h, uint16_t& l) {
  __half hh = __float2half_rn(v);
  h = __half_as_ushort(hh);
  l = __half_as_ushort(__float2half_rn((v - __half2float(hh)) * 2048.0f));
}

// async global->LDS, 16B/lane; lds base wave-uniform (HW adds lane*16)
__device__ __forceinline__ void gll16(const void* g, void* l) {
  __builtin_amdgcn_global_load_lds(
      (const __attribute__((address_space(1))) uint32_t*)g,
      (__attribute__((address_space(3))) uint32_t*)l, 16, 0, 0);
}

// ------------------------- CSR build -------------------------
__global__ void k_hist(const int* __restrict__ tgt, int* __restrict__ cnt, int E) {
  int e = blockIdx.x * 256 + threadIdx.x;
  if (e < E) atomicAdd(&cnt[tgt[e]], 1);
}

__global__ __launch_bounds__(256) void k_scan1(const int* __restrict__ cnt,
                                               int* __restrict__ row_start,
                                               int* __restrict__ bsum,
                                               float* __restrict__ dinv, int n) {
  int tid = threadIdx.x;
  int i = blockIdx.x * 256 + tid;
  int c = (i < n) ? cnt[i] : 0;
  if (i < n) dinv[i] = rsqrtf((float)(c + 1));  // +1 self-loop
  int lane = tid & 63, wv = tid >> 6;
  int v = c;
#pragma unroll
  for (int d = 1; d < 64; d <<= 1) {
    int u = __shfl_up(v, d);
    if (lane >= d) v += u;
  }
  __shared__ int ws[4];
  if (lane == 63) ws[wv] = v;
  __syncthreads();
  int add = 0;
#pragma unroll
  for (int w = 0; w < 4; ++w)
    if (w < wv) add += ws[w];
  int incl = v + add;
  if (i < n) row_start[i] = incl - c;
  if (tid == 255) bsum[blockIdx.x] = incl;
}

__global__ __launch_bounds__(256) void k_scan2(const int* __restrict__ bsum,
                                               int* __restrict__ bbase,
                                               int* __restrict__ row_start,
                                               int nb, int n) {
  int tid = threadIdx.x;
  int c = (tid < nb) ? bsum[tid] : 0;
  int lane = tid & 63, wv = tid >> 6;
  int v = c;
#pragma unroll
  for (int d = 1; d < 64; d <<= 1) {
    int u = __shfl_up(v, d);
    if (lane >= d) v += u;
  }
  __shared__ int ws[4];
  if (lane == 63) ws[wv] = v;
  __syncthreads();
  int add = 0;
#pragma unroll
  for (int w = 0; w < 4; ++w)
    if (w < wv) add += ws[w];
  int incl = v + add;
  if (tid < nb) bbase[tid] = incl - c;
  if (tid == 255) row_start[n] = incl;
}

__global__ void k_scan3(int* __restrict__ row_start, const int* __restrict__ bbase, int n) {
  int i = blockIdx.x * 256 + threadIdx.x;
  if (i < n) row_start[i] += bbase[blockIdx.x];
}

__global__ void k_scatter(const int* __restrict__ src, const int* __restrict__ tgt,
                          const int* __restrict__ row_start, int* __restrict__ cursor,
                          int* __restrict__ csr_src, int E) {
  int e = blockIdx.x * 256 + threadIdx.x;
  if (e >= E) return;
  int t = tgt[e];
  int pos = atomicAdd(&cursor[t], 1);
  csr_src[row_start[t] + pos] = src[e];
}

// ------------------------- fused weight transpose + f16 hi/lo' split --------------
__global__ void k_cvtW3(const float* __restrict__ W1, uint16_t* __restrict__ W1h,
                        uint16_t* __restrict__ W1l,
                        const float* __restrict__ W2, uint16_t* __restrict__ W2h,
                        uint16_t* __restrict__ W2l,
                        const float* __restrict__ W3, uint16_t* __restrict__ W3h,
                        uint16_t* __restrict__ W3l) {
  const int T1 = 256 * 128, T2 = 128 * 256, T3 = 64 * 128;
  int i = blockIdx.x * 256 + threadIdx.x;
  if (i < T1) {
    int nn = i >> 7, kk = i & 127;                  // K=128, N=256
    split16(W1[(size_t)kk * 256 + nn], W1h[i], W1l[i]);
  } else if (i < T1 + T2) {
    int j = i - T1;
    int nn = j >> 8, kk = j & 255;                  // K=256, N=128
    split16(W2[(size_t)kk * 128 + nn], W2h[j], W2l[j]);
  } else if (i < T1 + T2 + T3) {
    int j = i - T1 - T2;
    int nn = j >> 7, kk = j & 127;                  // K=128, N=64
    split16(W3[(size_t)kk * 64 + nn], W3h[j], W3l[j]);
  }
}

// ------------------------- xs16 = f16(x*dinv) + BOTH dropout masks ---------------
// One wave per row t: 64 lanes x float2 (512B row), then 6 threefry ballots
// (mask1[t][0..3] for h1's 256 cols, mask2[t][0..1] for h2's 128 cols) hidden
// under the streaming loads' latency.
__global__ __launch_bounds__(256) void k_scale_mask(const float* __restrict__ x,
                                                    const float* __restrict__ dinv,
                                                    uint16_t* __restrict__ xs,
                                                    uint64_t* __restrict__ mask1,
                                                    uint64_t* __restrict__ mask2,
                                                    uint32_t a0, uint32_t a1,
                                                    uint32_t b0, uint32_t b1, int n) {
  int gw = (int)((blockIdx.x * 256 + threadIdx.x) >> 6);
  if (gw >= n) return;
  int lane = threadIdx.x & 63;
  int t = gw;
  float2 v = ((const float2*)x)[(size_t)t * 64 + lane];
  float s = dinv[t];
  __half2 h;
  h.x = __float2half_rn(v.x * s);
  h.y = __float2half_rn(v.y * s);
  ((__half2*)xs)[(size_t)t * 64 + lane] = h;
#pragma unroll
  for (int w = 0; w < 4; ++w) {
    bool kp = drop_keep(a0, a1, (uint32_t)t * 256u + (uint32_t)(w * 64 + lane));
    uint64_t m = __ballot(kp);
    if (lane == 0) mask1[(size_t)t * 4 + w] = m;
  }
#pragma unroll
  for (int w = 0; w < 2; ++w) {
    bool kp = drop_keep(b0, b1, (uint32_t)t * 128u + (uint32_t)(w * 64 + lane));
    uint64_t m = __ballot(kp);
    if (lane == 0) mask2[(size_t)t * 2 + w] = m;
  }
}

// ------------------------- split-f16 MFMA GEMM, barrier-free, A-in-regs ----------
// Grid (Mpad/128, N/(TPB*64)). Block: 4 waves, each 32 rows x 64 cols per tile.
// B tiles (TPB x 64 cols x K, hi+lo') staged to LDS once (XOR-swizzled source);
// A fragments loaded ONCE global->reg (whole K), reused across TPB col-tiles.
// MODE 0: C16=f16(v*sb[row]);  MODE 1: Cf=v+sb[col];  MODE 2: C16=f16(relu(mask?v*1.25:0))
template <int TPB, bool ASPLIT, int MODE, int K>
__global__ __launch_bounds__(256, 2) void k_mfma(
    const uint16_t* __restrict__ Ah, const uint16_t* __restrict__ Al,
    const uint16_t* __restrict__ Bh, const uint16_t* __restrict__ Bl,
    const float* __restrict__ sb, float* __restrict__ Cf,
    uint16_t* __restrict__ C16, const uint64_t* __restrict__ mask,
    int M, int N) {
  constexpr int CHT = 64 * (K / 8);      // 16B chunks per B array per tile
  constexpr int KS = K / 32;
  extern __shared__ uint16_t lB[];       // TPB x { hi 64*K, lo 64*K }

  int tid = threadIdx.x;
  int lane = tid & 63;
  int wid = tid >> 6;
  int r16 = lane & 15, kq = lane >> 4;
  int bm = blockIdx.x * 128, bn0 = blockIdx.y * (TPB * 64);

  // ---- stage all B tiles (async) ----
#pragma unroll
  for (int tt = 0; tt < TPB; ++tt) {
#pragma unroll
    for (int p = 0; p < (2 * CHT) / 256; ++p) {
      int c = p * 256 + tid;
      int arr = (c >= CHT);
      int cc = arr ? c - CHT : c;
      int row = cc / (K / 8), u = cc - row * (K / 8);
      int seg = u ^ (row & 7);  // inverse-swizzled source
      const uint16_t* src = (arr ? Bl : Bh) + (size_t)(bn0 + tt * 64 + row) * K + seg * 8;
      gll16(src, lB + (size_t)(tt * (2 * CHT) + p * 256 + (wid << 6)) * 8);
    }
  }

  // ---- load A fragments once (overlaps B staging latency) ----
  int mrow0 = bm + wid * 32;
  s8v aH[2][KS], aL[2][KS];
#pragma unroll
  for (int mb = 0; mb < 2; ++mb)
#pragma unroll
    for (int ks = 0; ks < KS; ++ks) {
      size_t ga = (size_t)(mrow0 + mb * 16 + r16) * K + ks * 32 + kq * 8;
      aH[mb][ks] = *(const s8v*)&Ah[ga];
      if (ASPLIT) aL[mb][ks] = *(const s8v*)&Al[ga];
    }

  asm volatile("s_waitcnt vmcnt(0)" ::: "memory");
  __syncthreads();

#pragma unroll
  for (int tt = 0; tt < TPB; ++tt) {
    const uint16_t* tbh = lB + (size_t)tt * (2 * 64 * K);
    const uint16_t* tbl = tbh + 64 * K;
    f4v accH[2][4] = {};
    f4v accL[2][4] = {};
#pragma unroll
    for (int ks = 0; ks < KS; ++ks) {
      s8v bh[4], bl[4];
#pragma unroll
      for (int nb = 0; nb < 4; ++nb) {
        int brow = nb * 16 + r16;
        int u = (ks * 4 + kq) ^ (brow & 7);
        bh[nb] = *(const s8v*)&tbh[brow * K + u * 8];
        bl[nb] = *(const s8v*)&tbl[brow * K + u * 8];
      }
#pragma unroll
      for (int mb = 0; mb < 2; ++mb) {
#pragma unroll
        for (int nb = 0; nb < 4; ++nb)
          accH[mb][nb] = __builtin_amdgcn_mfma_f32_16x16x32_f16(aH[mb][ks], bh[nb], accH[mb][nb], 0, 0, 0);
        if (ASPLIT) {
#pragma unroll
          for (int nb = 0; nb < 4; ++nb) {
            accL[mb][nb] = __builtin_amdgcn_mfma_f32_16x16x32_f16(aH[mb][ks], bl[nb], accL[mb][nb], 0, 0, 0);
            accL[mb][nb] = __builtin_amdgcn_mfma_f32_16x16x32_f16(aL[mb][ks], bh[nb], accL[mb][nb], 0, 0, 0);
          }
        } else {
#pragma unroll
          for (int nb = 0; nb < 4; ++nb)
            accL[mb][nb] = __builtin_amdgcn_mfma_f32_16x16x32_f16(aH[mb][ks], bl[nb], accL[mb][nb], 0, 0, 0);
        }
      }
    }
    // ---- epilogue for tile tt ----
#pragma unroll
    for (int mb = 0; mb < 2; ++mb) {
#pragma unroll
      for (int nb = 0; nb < 4; ++nb) {
        int col = bn0 + tt * 64 + nb * 16 + r16;
#pragma unroll
        for (int r = 0; r < 4; ++r) {
          int row = mrow0 + mb * 16 + kq * 4 + r;
          if (row >= M) continue;
          float v = accH[mb][nb][r] + accL[mb][nb][r] * (1.0f / 2048.0f);
          size_t o = (size_t)row * N + col;
          if (MODE == 0) {
            C16[o] = __half_as_ushort(__float2half_rn(v * sb[row]));
          } else if (MODE == 1) {
            Cf[o] = v + sb[col];
          } else {
            v += sb[col];
            uint64_t m = mask[(size_t)row * (N >> 6) + (col >> 6)];
            v = ((m >> (col & 63)) & 1ull) ? fmaxf(v * 1.25f, 0.f) : 0.f;
            C16[o] = __half_as_ushort(__float2half_rn(v));
          }
        }
      }
    }
  }
}

// ------------------------- layer-1 aggregation (pure gather, MLP-8) ---------------
__global__ __launch_bounds__(256) void k_agg_x(const uint16_t* __restrict__ xs,
                                               const float* __restrict__ dinv,
                                               const int* __restrict__ row_start,
                                               const int* __restrict__ csr_src,
                                               uint32_t* __restrict__ outh,
                                               uint32_t* __restrict__ outl, int n) {
  const int F = 128;
  int wid = (int)((blockIdx.x * 256 + threadIdx.x) >> 6);
  if (wid >= n) return;
  int lane = threadIdx.x & 63;
  int t = wid;
  float2 a[8];
  a[0] = __half22float2(((const __half2*)(xs + (size_t)t * F))[lane]);
#pragma unroll
  for (int q = 1; q < 8; ++q) a[q] = make_float2(0.f, 0.f);
  int e0 = row_start[t], e1 = row_start[t + 1];
  int e = e0;
  for (; e + 8 <= e1; e += 8) {
#pragma unroll
    for (int q = 0; q < 8; ++q) {
      int s = csr_src[e + q];
      float2 v = __half22float2(((const __half2*)(xs + (size_t)s * F))[lane]);
      a[q].x += v.x;
      a[q].y += v.y;
    }
  }
  for (; e < e1; ++e) {
    int s = csr_src[e];
    float2 v = __half22float2(((const __half2*)(xs + (size_t)s * F))[lane]);
    a[0].x += v.x; a[0].y += v.y;
  }
  float dt = dinv[t];
  float rx = (((a[0].x + a[1].x) + (a[2].x + a[3].x)) + ((a[4].x + a[5].x) + (a[6].x + a[7].x))) * dt;
  float ry = (((a[0].y + a[1].y) + (a[2].y + a[3].y)) + ((a[4].y + a[5].y) + (a[6].y + a[7].y))) * dt;
  uint16_t hx, lx, hy, ly;
  split16(rx, hx, lx);
  split16(ry, hy, ly);
  outh[(size_t)t * 64 + lane] = (uint32_t)hx | ((uint32_t)hy << 16);
  outl[(size_t)t * 64 + lane] = (uint32_t)lx | ((uint32_t)ly << 16);
}

// ------------------------- layer-2 aggregation + bias + mask-drop + relu ----------
__global__ __launch_bounds__(256) void k_agg_w(const uint16_t* __restrict__ hws,
                                               const float* __restrict__ dinv,
                                               const float* __restrict__ bias,
                                               const int* __restrict__ row_start,
                                               const int* __restrict__ csr_src,
                                               uint32_t* __restrict__ outh,
                                               uint32_t* __restrict__ outl,
                                               const uint64_t* __restrict__ mask2, int n) {
  const int F = 128;
  int wid = (int)((blockIdx.x * 256 + threadIdx.x) >> 6);
  if (wid >= n) return;
  int lane = threadIdx.x & 63;
  int t = wid;
  float2 a[8];
  a[0] = __half22float2(((const __half2*)(hws + (size_t)t * F))[lane]);
#pragma unroll
  for (int q = 1; q < 8; ++q) a[q] = make_float2(0.f, 0.f);
  int e0 = row_start[t], e1 = row_start[t + 1];
  int e = e0;
  for (; e + 8 <= e1; e += 8) {
#pragma unroll
    for (int q = 0; q < 8; ++q) {
      int s = csr_src[e + q];
      float2 v = __half22float2(((const __half2*)(hws + (size_t)s * F))[lane]);
      a[q].x += v.x;
      a[q].y += v.y;
    }
  }
  for (; e < e1; ++e) {
    int s = csr_src[e];
    float2 v = __half22float2(((const __half2*)(hws + (size_t)s * F))[lane]);
    a[0].x += v.x; a[0].y += v.y;
  }
  float d = dinv[t];
  float sx = ((a[0].x + a[1].x) + (a[2].x + a[3].x)) + ((a[4].x + a[5].x) + (a[6].x + a[7].x));
  float sy = ((a[0].y + a[1].y) + (a[2].y + a[3].y)) + ((a[4].y + a[5].y) + (a[6].y + a[7].y));
  float vx = sx * d + bias[lane * 2];
  float vy = sy * d + bias[lane * 2 + 1];
  uint64_t m = mask2[(size_t)t * 2 + (lane >> 5)];
  int bit = (lane * 2) & 63;
  vx = ((m >> bit) & 1ull)       ? fmaxf(vx * 1.25f, 0.f) : 0.f;
  vy = ((m >> (bit + 1)) & 1ull) ? fmaxf(vy * 1.25f, 0.f) : 0.f;
  uint16_t hx, lx, hy, ly;
  split16(vx, hx, lx);
  split16(vy, hy, ly);
  outh[(size_t)t * 64 + lane] = (uint32_t)hx | ((uint32_t)hy << 16);
  outl[(size_t)t * 64 + lane] = (uint32_t)lx | ((uint32_t)ly << 16);
}

// ------------------------- launch -------------------------
static inline size_t ws_align(size_t x) { return (x + 255) & ~(size_t)255; }

extern "C" void kernel_launch(void* const* d_in, const int* in_sizes, int n_in,
                              void* d_out, int out_size, void* d_ws, size_t ws_size,
                              hipStream_t stream) {
  const float* x  = (const float*)d_in[0];
  const float* W1 = (const float*)d_in[1];
  const float* b1 = (const float*)d_in[2];
  const float* W2 = (const float*)d_in[3];
  const float* b2 = (const float*)d_in[4];
  const float* W3 = (const float*)d_in[5];
  const float* b3 = (const float*)d_in[6];
  const int*   ei = (const int*)d_in[7];

  const int IN = 128, H2 = 256, HID = 128, OD = 64;
  const int n = in_sizes[0] / IN;   // 50000
  const int E = in_sizes[7] / 2;    // 800000
  const int* esrc = ei;
  const int* etgt = ei + E;
  const int nb = (n + 255) / 256;
  const int Mb128 = (n + 127) / 128;  // 391
  const int Mpad = Mb128 * 128;       // 50048

  char* w = (char*)d_ws;
  size_t off = 0;
  auto alloc = [&](size_t bytes) { void* p = w + off; off += ws_align(bytes); return p; };
  float*    dinv      = (float*)alloc((size_t)n * 4);
  int*      cnt       = (int*)alloc((size_t)n * 4);
  int*      cursor    = (int*)alloc((size_t)n * 4);   // adjacent to cnt (one memset)
  int*      row_start = (int*)alloc(((size_t)n + 1) * 4);
  int*      bsum      = (int*)alloc(256 * 4);
  int*      bbase     = (int*)alloc(256 * 4);
  int*      csr_src   = (int*)alloc((size_t)E * 4);
  uint16_t* xs16      = (uint16_t*)alloc((size_t)n * IN * 2);
  uint16_t* A1h       = (uint16_t*)alloc((size_t)Mpad * IN * 2);   // ag / h2 hi (aliased)
  uint16_t* A1l       = (uint16_t*)alloc((size_t)Mpad * IN * 2);   // ag / h2 lo'
  uint16_t* h1_16     = (uint16_t*)alloc((size_t)Mpad * H2 * 2);   // h1 single f16
  uint16_t* hw2_16    = (uint16_t*)alloc((size_t)n * HID * 2);
  uint64_t* mask1     = (uint64_t*)alloc((size_t)n * 4 * 8);
  uint64_t* mask2     = (uint64_t*)alloc((size_t)n * 2 * 8);
  uint16_t* Wt1h      = (uint16_t*)alloc((size_t)H2 * IN * 2);
  uint16_t* Wt1l      = (uint16_t*)alloc((size_t)H2 * IN * 2);
  uint16_t* Wt2h      = (uint16_t*)alloc((size_t)HID * H2 * 2);
  uint16_t* Wt2l      = (uint16_t*)alloc((size_t)HID * H2 * 2);
  uint16_t* Wt3h      = (uint16_t*)alloc((size_t)OD * IN * 2);
  uint16_t* Wt3l      = (uint16_t*)alloc((size_t)OD * IN * 2);
  (void)ws_size;

  hipFuncSetAttribute((const void*)&k_mfma<2, true, 2, 128>,
                      hipFuncAttributeMaxDynamicSharedMemorySize, 65536);
  hipFuncSetAttribute((const void*)&k_mfma<1, false, 0, 256>,
                      hipFuncAttributeMaxDynamicSharedMemorySize, 65536);
  hipFuncSetAttribute((const void*)&k_mfma<1, true, 1, 128>,
                      hipFuncAttributeMaxDynamicSharedMemorySize, 32768);

  uint32_t dk1_0, dk1_1, dk2_0, dk2_1;
  threefry2x32(0u, 42u, 0u, 0u, dk1_0, dk1_1);
  threefry2x32(0u, 42u, 0u, 1u, dk2_0, dk2_1);

  // single memset covers cnt + cursor (adjacent allocations)
  hipMemsetAsync(cnt, 0, ws_align((size_t)n * 4) + (size_t)n * 4, stream);

  k_cvtW3<<<(256 * 128 + 128 * 256 + 64 * 128 + 255) / 256, 256, 0, stream>>>(
      W1, Wt1h, Wt1l, W2, Wt2h, Wt2l, W3, Wt3h, Wt3l);

  k_hist<<<(E + 255) / 256, 256, 0, stream>>>(etgt, cnt, E);
  k_scan1<<<nb, 256, 0, stream>>>(cnt, row_start, bsum, dinv, n);
  k_scan2<<<1, 256, 0, stream>>>(bsum, bbase, row_start, nb, n);
  k_scan3<<<nb, 256, 0, stream>>>(row_start, bbase, n);
  k_scatter<<<(E + 255) / 256, 256, 0, stream>>>(esrc, etgt, row_start, cursor, csr_src, E);

  // layer 1: scale+masks (threefry hidden under streaming), pure-gather agg, GEMM1
  k_scale_mask<<<(n * 64 + 255) / 256, 256, 0, stream>>>(x, dinv, xs16, mask1, mask2,
                                                         dk1_0, dk1_1, dk2_0, dk2_1, n);
  k_agg_x<<<(n + 3) / 4, 256, 0, stream>>>(xs16, dinv, row_start, csr_src,
                                           (uint32_t*)A1h, (uint32_t*)A1l, n);
  {
    dim3 g(Mb128, 2);  // 2 col-tiles per block x 2 = 256 cols
    k_mfma<2, true, 2, 128><<<g, 256, 65536, stream>>>(A1h, A1l, Wt1h, Wt1l, b1, nullptr,
                                                       h1_16, mask1, n, H2);
  }

  // layer 2
  {
    dim3 g(Mb128, 2);
    k_mfma<1, false, 0, 256><<<g, 256, 65536, stream>>>(h1_16, nullptr, Wt2h, Wt2l, dinv,
                                                        nullptr, hw2_16, nullptr, n, HID);
  }
  k_agg_w<<<(n + 3) / 4, 256, 0, stream>>>(hw2_16, dinv, b2, row_start, csr_src,
                                           (uint32_t*)A1h, (uint32_t*)A1l, mask1 /*unused*/ == nullptr ? nullptr : mask2, n);

  // layer 3
  {
    dim3 g(Mb128, 1);
    k_mfma<1, true, 1, 128><<<g, 256, 32768, stream>>>(A1h, A1l, Wt3h, Wt3l, b3,
                                                       (float*)d_out, nullptr, nullptr, n, OD);
  }
}

// Round 14
// 262.501 us; speedup vs baseline: 1.1618x; 1.1618x over previous
//
#include <hip/hip_runtime.h>
#include <hip/hip_fp16.h>
#include <stdint.h>

// ---------------------------------------------------------------------------
// GCN 3-layer forward, MI355X. Round 14 (base = r12, r13 reverted):
//  - A-side split DROPPED everywhere: ag/h1/h2/hw2 all single f16 (error
//    budget ~1.4e-4/elem vs 1.8e-3 headroom). GEMMs do 2 MFMA passes (Ah*Bh,
//    Ah*Bl); weights keep hi+lo' (B-side split preserved).
//  - GEMM occupancy: K=128 GEMMs TPB=1/32KB LDS/launch_bounds(256,4) -> 4
//    blocks/CU (r13 PMC: 54us GEMM-1 with ALL pipes idle at 14% occupancy).
//  - XCD-aware grid decode: all col-tiles of a row-panel on one XCD -> A
//    re-reads are L2 hits.
//  - threefry: r12 placement (agg_x ballots -> mask1; agg_w inline).
// ---------------------------------------------------------------------------

typedef __attribute__((ext_vector_type(8))) short s8v;   // 8 f16 (4 VGPR)
typedef __attribute__((ext_vector_type(4))) float f4v;   // 4 f32 acc

__device__ __host__ __forceinline__ uint32_t tf_rotl(uint32_t v, int r) {
  return (v << r) | (v >> (32 - r));
}

__device__ __host__ __forceinline__ void threefry2x32(uint32_t k0, uint32_t k1,
                                                      uint32_t x0, uint32_t x1,
                                                      uint32_t& o0, uint32_t& o1) {
  const uint32_t k2 = k0 ^ k1 ^ 0x1BD11BDAu;
  x0 += k0; x1 += k1;
#define TFR(r) { x0 += x1; x1 = tf_rotl(x1, r); x1 ^= x0; }
  TFR(13) TFR(15) TFR(26) TFR(6)
  x0 += k1; x1 += k2 + 1u;
  TFR(17) TFR(29) TFR(16) TFR(24)
  x0 += k2; x1 += k0 + 2u;
  TFR(13) TFR(15) TFR(26) TFR(6)
  x0 += k0; x1 += k1 + 3u;
  TFR(17) TFR(29) TFR(16) TFR(24)
  x0 += k1; x1 += k2 + 4u;
  TFR(13) TFR(15) TFR(26) TFR(6)
  x0 += k2; x1 += k0 + 5u;
#undef TFR
  o0 = x0; o1 = x1;
}

__device__ __forceinline__ bool drop_keep(uint32_t k0, uint32_t k1, uint32_t j) {
  uint32_t a, b;
  threefry2x32(k0, k1, 0u, j, a, b);
  uint32_t bits = a ^ b;
  float u = __uint_as_float((bits >> 9) | 0x3f800000u) - 1.0f;
  return u < 0.8f;
}

// f16 hi / scaled-lo helper (weights only now)
__device__ __forceinline__ void split16(float v, uint16_t& h, uint16_t& l) {
  __half hh = __float2half_rn(v);
  h = __half_as_ushort(hh);
  l = __half_as_ushort(__float2half_rn((v - __half2float(hh)) * 2048.0f));
}

// async global->LDS, 16B/lane; lds base wave-uniform (HW adds lane*16)
__device__ __forceinline__ void gll16(const void* g, void* l) {
  __builtin_amdgcn_global_load_lds(
      (const __attribute__((address_space(1))) uint32_t*)g,
      (__attribute__((address_space(3))) uint32_t*)l, 16, 0, 0);
}

// ------------------------- CSR build -------------------------
__global__ void k_hist(const int* __restrict__ tgt, int* __restrict__ cnt, int E) {
  int e = blockIdx.x * 256 + threadIdx.x;
  if (e < E) atomicAdd(&cnt[tgt[e]], 1);
}

__global__ __launch_bounds__(256) void k_scan1(const int* __restrict__ cnt,
                                               int* __restrict__ row_start,
                                               int* __restrict__ bsum,
                                               float* __restrict__ dinv, int n) {
  int tid = threadIdx.x;
  int i = blockIdx.x * 256 + tid;
  int c = (i < n) ? cnt[i] : 0;
  if (i < n) dinv[i] = rsqrtf((float)(c + 1));  // +1 self-loop
  int lane = tid & 63, wv = tid >> 6;
  int v = c;
#pragma unroll
  for (int d = 1; d < 64; d <<= 1) {
    int u = __shfl_up(v, d);
    if (lane >= d) v += u;
  }
  __shared__ int ws[4];
  if (lane == 63) ws[wv] = v;
  __syncthreads();
  int add = 0;
#pragma unroll
  for (int w = 0; w < 4; ++w)
    if (w < wv) add += ws[w];
  int incl = v + add;
  if (i < n) row_start[i] = incl - c;
  if (tid == 255) bsum[blockIdx.x] = incl;
}

__global__ __launch_bounds__(256) void k_scan2(const int* __restrict__ bsum,
                                               int* __restrict__ bbase,
                                               int* __restrict__ row_start,
                                               int nb, int n) {
  int tid = threadIdx.x;
  int c = (tid < nb) ? bsum[tid] : 0;
  int lane = tid & 63, wv = tid >> 6;
  int v = c;
#pragma unroll
  for (int d = 1; d < 64; d <<= 1) {
    int u = __shfl_up(v, d);
    if (lane >= d) v += u;
  }
  __shared__ int ws[4];
  if (lane == 63) ws[wv] = v;
  __syncthreads();
  int add = 0;
#pragma unroll
  for (int w = 0; w < 4; ++w)
    if (w < wv) add += ws[w];
  int incl = v + add;
  if (tid < nb) bbase[tid] = incl - c;
  if (tid == 255) row_start[n] = incl;
}

__global__ void k_scan3(int* __restrict__ row_start, const int* __restrict__ bbase, int n) {
  int i = blockIdx.x * 256 + threadIdx.x;
  if (i < n) row_start[i] += bbase[blockIdx.x];
}

__global__ void k_scatter(const int* __restrict__ src, const int* __restrict__ tgt,
                          const int* __restrict__ row_start, int* __restrict__ cursor,
                          int* __restrict__ csr_src, int E) {
  int e = blockIdx.x * 256 + threadIdx.x;
  if (e >= E) return;
  int t = tgt[e];
  int pos = atomicAdd(&cursor[t], 1);
  csr_src[row_start[t] + pos] = src[e];
}

// ------------------------- fused weight transpose + f16 hi/lo' split --------------
__global__ void k_cvtW3(const float* __restrict__ W1, uint16_t* __restrict__ W1h,
                        uint16_t* __restrict__ W1l,
                        const float* __restrict__ W2, uint16_t* __restrict__ W2h,
                        uint16_t* __restrict__ W2l,
                        const float* __restrict__ W3, uint16_t* __restrict__ W3h,
                        uint16_t* __restrict__ W3l) {
  const int T1 = 256 * 128, T2 = 128 * 256, T3 = 64 * 128;
  int i = blockIdx.x * 256 + threadIdx.x;
  if (i < T1) {
    int nn = i >> 7, kk = i & 127;                  // K=128, N=256
    split16(W1[(size_t)kk * 256 + nn], W1h[i], W1l[i]);
  } else if (i < T1 + T2) {
    int j = i - T1;
    int nn = j >> 8, kk = j & 255;                  // K=256, N=128
    split16(W2[(size_t)kk * 128 + nn], W2h[j], W2l[j]);
  } else if (i < T1 + T2 + T3) {
    int j = i - T1 - T2;
    int nn = j >> 7, kk = j & 127;                  // K=128, N=64
    split16(W3[(size_t)kk * 64 + nn], W3h[j], W3l[j]);
  }
}

// ------------------------- xs16 = f16(x * dinv[row]) -------------------------
__global__ void k_scale16(const float* __restrict__ x, const float* __restrict__ dinv,
                          uint16_t* __restrict__ xs, int total2) {
  int i = blockIdx.x * 256 + threadIdx.x;
  if (i >= total2) return;
  float2 v = ((const float2*)x)[i];
  float s = dinv[i >> 6];
  __half2 h;
  h.x = __float2half_rn(v.x * s);
  h.y = __float2half_rn(v.y * s);
  ((__half2*)xs)[i] = h;
}

// ------------------------- f16 MFMA GEMM, barrier-free, XCD-swizzled grid --------
// 1-D grid: xcd=id&7, ct=(id>>3)%CTN, rb=((id>>3)/CTN)*8+xcd (rb>=RB -> exit).
// Block: 4 waves, 128 rows x 64 cols. B tile (64 cols x K, hi+lo') in LDS once;
// A fragments (single f16) global->reg once. 2 MFMA passes: Ah*Bh, Ah*Bl.
// MODE 0: C16=f16(v*sb[row]);  MODE 1: Cf=v+sb[col];  MODE 2: C16=f16(relu(mask?v*1.25:0))
template <int MODE, int K>
__global__ __launch_bounds__(256, K == 128 ? 4 : 2) void k_mfma(
    const uint16_t* __restrict__ Ah,
    const uint16_t* __restrict__ Bh, const uint16_t* __restrict__ Bl,
    const float* __restrict__ sb, float* __restrict__ Cf,
    uint16_t* __restrict__ C16, const uint64_t* __restrict__ mask,
    int M, int N, int CTN, int RB) {
  constexpr int SEGS = K / 8;
  constexpr int CHT = 64 * SEGS;         // 16B chunks per B array
  constexpr int KS = K / 32;
  extern __shared__ uint16_t lB[];       // hi CHT*8, lo CHT*8

  int id = blockIdx.x;
  int xcd = id & 7;
  int q = id >> 3;
  int ct = q % CTN;
  int rb = (q / CTN) * 8 + xcd;
  if (rb >= RB) return;

  int tid = threadIdx.x;
  int lane = tid & 63;
  int wid = tid >> 6;
  int r16 = lane & 15, kq = lane >> 4;
  int bm = rb * 128, bn0 = ct * 64;

  // ---- stage B tile (hi + lo') once ----
#pragma unroll
  for (int p = 0; p < (2 * CHT) / 256; ++p) {
    int c = p * 256 + tid;
    int arr = (c >= CHT);
    int cc = arr ? c - CHT : c;
    int row = cc / SEGS, u = cc - row * SEGS;
    int seg = u ^ (row & 7);  // inverse-swizzled source
    const uint16_t* src = (arr ? Bl : Bh) + (size_t)(bn0 + row) * K + seg * 8;
    gll16(src, lB + (size_t)(p * 256 + (wid << 6)) * 8);
  }

  // ---- load A fragments once (overlaps B staging latency) ----
  int mrow0 = bm + wid * 32;
  s8v aH[2][KS];
#pragma unroll
  for (int mb = 0; mb < 2; ++mb)
#pragma unroll
    for (int ks = 0; ks < KS; ++ks) {
      size_t ga = (size_t)(mrow0 + mb * 16 + r16) * K + ks * 32 + kq * 8;
      aH[mb][ks] = *(const s8v*)&Ah[ga];
    }

  asm volatile("s_waitcnt vmcnt(0)" ::: "memory");
  __syncthreads();

  const uint16_t* tbh = lB;
  const uint16_t* tbl = lB + (size_t)CHT * 8;
  f4v accH[2][4] = {};
  f4v accL[2][4] = {};
#pragma unroll
  for (int ks = 0; ks < KS; ++ks) {
    s8v bh[4], bl[4];
#pragma unroll
    for (int nb = 0; nb < 4; ++nb) {
      int brow = nb * 16 + r16;
      int u = (ks * 4 + kq) ^ (brow & 7);
      bh[nb] = *(const s8v*)&tbh[brow * K + u * 8];
      bl[nb] = *(const s8v*)&tbl[brow * K + u * 8];
    }
#pragma unroll
    for (int mb = 0; mb < 2; ++mb) {
#pragma unroll
      for (int nb = 0; nb < 4; ++nb) {
        accH[mb][nb] = __builtin_amdgcn_mfma_f32_16x16x32_f16(aH[mb][ks], bh[nb], accH[mb][nb], 0, 0, 0);
        accL[mb][nb] = __builtin_amdgcn_mfma_f32_16x16x32_f16(aH[mb][ks], bl[nb], accL[mb][nb], 0, 0, 0);
      }
    }
  }

  // ---- epilogue ----
#pragma unroll
  for (int mb = 0; mb < 2; ++mb) {
#pragma unroll
    for (int nb = 0; nb < 4; ++nb) {
      int col = bn0 + nb * 16 + r16;
#pragma unroll
      for (int r = 0; r < 4; ++r) {
        int row = mrow0 + mb * 16 + kq * 4 + r;
        if (row >= M) continue;
        float v = accH[mb][nb][r] + accL[mb][nb][r] * (1.0f / 2048.0f);
        size_t o = (size_t)row * N + col;
        if (MODE == 0) {
          C16[o] = __half_as_ushort(__float2half_rn(v * sb[row]));
        } else if (MODE == 1) {
          Cf[o] = v + sb[col];
        } else {
          v += sb[col];
          uint64_t m = mask[(size_t)row * (N >> 6) + (col >> 6)];
          v = ((m >> (col & 63)) & 1ull) ? fmaxf(v * 1.25f, 0.f) : 0.f;
          C16[o] = __half_as_ushort(__float2half_rn(v));
        }
      }
    }
  }
}

// ------------------------- layer-1 aggregation (MLP-8) + mask1 ballots ------------
__global__ __launch_bounds__(256) void k_agg_x(const uint16_t* __restrict__ xs,
                                               const float* __restrict__ dinv,
                                               const int* __restrict__ row_start,
                                               const int* __restrict__ csr_src,
                                               uint32_t* __restrict__ out,
                                               uint64_t* __restrict__ mask1,
                                               uint32_t k0, uint32_t k1, int n) {
  const int F = 128;
  int wid = (int)((blockIdx.x * 256 + threadIdx.x) >> 6);
  if (wid >= n) return;
  int lane = threadIdx.x & 63;
  int t = wid;
  float2 a[8];
  a[0] = __half22float2(((const __half2*)(xs + (size_t)t * F))[lane]);
#pragma unroll
  for (int q = 1; q < 8; ++q) a[q] = make_float2(0.f, 0.f);
  int e0 = row_start[t], e1 = row_start[t + 1];
  int e = e0;
  for (; e + 8 <= e1; e += 8) {
#pragma unroll
    for (int q = 0; q < 8; ++q) {
      int s = csr_src[e + q];
      float2 v = __half22float2(((const __half2*)(xs + (size_t)s * F))[lane]);
      a[q].x += v.x;
      a[q].y += v.y;
    }
  }
  for (; e < e1; ++e) {
    int s = csr_src[e];
    float2 v = __half22float2(((const __half2*)(xs + (size_t)s * F))[lane]);
    a[0].x += v.x; a[0].y += v.y;
  }
  float dt = dinv[t];
  float rx = (((a[0].x + a[1].x) + (a[2].x + a[3].x)) + ((a[4].x + a[5].x) + (a[6].x + a[7].x))) * dt;
  float ry = (((a[0].y + a[1].y) + (a[2].y + a[3].y)) + ((a[4].y + a[5].y) + (a[6].y + a[7].y))) * dt;
  __half2 o;
  o.x = __float2half_rn(rx);
  o.y = __float2half_rn(ry);
  out[(size_t)t * 64 + lane] = *(uint32_t*)&o;
  // layer-1 dropout mask (hidden under gather latency): elem j = t*256 + w*64 + lane
#pragma unroll
  for (int w = 0; w < 4; ++w) {
    bool kp = drop_keep(k0, k1, (uint32_t)t * 256u + (uint32_t)(w * 64 + lane));
    uint64_t m = __ballot(kp);
    if (lane == 0) mask1[(size_t)t * 4 + w] = m;
  }
}

// ------------------------- layer-2 aggregation + bias + inline-drop + relu --------
__global__ __launch_bounds__(256) void k_agg_w(const uint16_t* __restrict__ hws,
                                               const float* __restrict__ dinv,
                                               const float* __restrict__ bias,
                                               const int* __restrict__ row_start,
                                               const int* __restrict__ csr_src,
                                               uint32_t* __restrict__ out,
                                               uint32_t k0, uint32_t k1, int n) {
  const int F = 128;
  int wid = (int)((blockIdx.x * 256 + threadIdx.x) >> 6);
  if (wid >= n) return;
  int lane = threadIdx.x & 63;
  int t = wid;
  float2 a[8];
  a[0] = __half22float2(((const __half2*)(hws + (size_t)t * F))[lane]);
#pragma unroll
  for (int q = 1; q < 8; ++q) a[q] = make_float2(0.f, 0.f);
  int e0 = row_start[t], e1 = row_start[t + 1];
  int e = e0;
  for (; e + 8 <= e1; e += 8) {
#pragma unroll
    for (int q = 0; q < 8; ++q) {
      int s = csr_src[e + q];
      float2 v = __half22float2(((const __half2*)(hws + (size_t)s * F))[lane]);
      a[q].x += v.x;
      a[q].y += v.y;
    }
  }
  for (; e < e1; ++e) {
    int s = csr_src[e];
    float2 v = __half22float2(((const __half2*)(hws + (size_t)s * F))[lane]);
    a[0].x += v.x; a[0].y += v.y;
  }
  float d = dinv[t];
  float sx = ((a[0].x + a[1].x) + (a[2].x + a[3].x)) + ((a[4].x + a[5].x) + (a[6].x + a[7].x));
  float sy = ((a[0].y + a[1].y) + (a[2].y + a[3].y)) + ((a[4].y + a[5].y) + (a[6].y + a[7].y));
  float vx = sx * d + bias[lane * 2];
  float vy = sy * d + bias[lane * 2 + 1];
  uint32_t j = (uint32_t)t * 128u + (uint32_t)lane * 2u;
  vx = drop_keep(k0, k1, j)     ? fmaxf(vx * 1.25f, 0.f) : 0.f;
  vy = drop_keep(k0, k1, j + 1) ? fmaxf(vy * 1.25f, 0.f) : 0.f;
  __half2 o;
  o.x = __float2half_rn(vx);
  o.y = __float2half_rn(vy);
  out[(size_t)t * 64 + lane] = *(uint32_t*)&o;
}

// ------------------------- launch -------------------------
static inline size_t ws_align(size_t x) { return (x + 255) & ~(size_t)255; }

extern "C" void kernel_launch(void* const* d_in, const int* in_sizes, int n_in,
                              void* d_out, int out_size, void* d_ws, size_t ws_size,
                              hipStream_t stream) {
  const float* x  = (const float*)d_in[0];
  const float* W1 = (const float*)d_in[1];
  const float* b1 = (const float*)d_in[2];
  const float* W2 = (const float*)d_in[3];
  const float* b2 = (const float*)d_in[4];
  const float* W3 = (const float*)d_in[5];
  const float* b3 = (const float*)d_in[6];
  const int*   ei = (const int*)d_in[7];

  const int IN = 128, H2 = 256, HID = 128, OD = 64;
  const int n = in_sizes[0] / IN;   // 50000
  const int E = in_sizes[7] / 2;    // 800000
  const int* esrc = ei;
  const int* etgt = ei + E;
  const int nb = (n + 255) / 256;
  const int Mb128 = (n + 127) / 128;  // 391
  const int Mpad = Mb128 * 128;       // 50048
  const int grpRB = (Mb128 + 7) / 8;  // 49

  char* w = (char*)d_ws;
  size_t off = 0;
  auto alloc = [&](size_t bytes) { void* p = w + off; off += ws_align(bytes); return p; };
  float*    dinv      = (float*)alloc((size_t)n * 4);
  int*      cnt       = (int*)alloc((size_t)n * 4);
  int*      cursor    = (int*)alloc((size_t)n * 4);   // adjacent to cnt (one memset)
  int*      row_start = (int*)alloc(((size_t)n + 1) * 4);
  int*      bsum      = (int*)alloc(256 * 4);
  int*      bbase     = (int*)alloc(256 * 4);
  int*      csr_src   = (int*)alloc((size_t)E * 4);
  uint16_t* xs16      = (uint16_t*)alloc((size_t)n * IN * 2);
  uint16_t* A1        = (uint16_t*)alloc((size_t)Mpad * IN * 2);   // ag / h2 (f16, aliased)
  uint16_t* h1_16     = (uint16_t*)alloc((size_t)Mpad * H2 * 2);   // h1 f16
  uint16_t* hw2_16    = (uint16_t*)alloc((size_t)n * HID * 2);
  uint64_t* mask1     = (uint64_t*)alloc((size_t)n * 4 * 8);
  uint16_t* Wt1h      = (uint16_t*)alloc((size_t)H2 * IN * 2);
  uint16_t* Wt1l      = (uint16_t*)alloc((size_t)H2 * IN * 2);
  uint16_t* Wt2h      = (uint16_t*)alloc((size_t)HID * H2 * 2);
  uint16_t* Wt2l      = (uint16_t*)alloc((size_t)HID * H2 * 2);
  uint16_t* Wt3h      = (uint16_t*)alloc((size_t)OD * IN * 2);
  uint16_t* Wt3l      = (uint16_t*)alloc((size_t)OD * IN * 2);
  (void)ws_size;

  hipFuncSetAttribute((const void*)&k_mfma<2, 128>,
                      hipFuncAttributeMaxDynamicSharedMemorySize, 32768);
  hipFuncSetAttribute((const void*)&k_mfma<0, 256>,
                      hipFuncAttributeMaxDynamicSharedMemorySize, 65536);
  hipFuncSetAttribute((const void*)&k_mfma<1, 128>,
                      hipFuncAttributeMaxDynamicSharedMemorySize, 32768);

  uint32_t dk1_0, dk1_1, dk2_0, dk2_1;
  threefry2x32(0u, 42u, 0u, 0u, dk1_0, dk1_1);
  threefry2x32(0u, 42u, 0u, 1u, dk2_0, dk2_1);

  // single memset covers cnt + cursor (adjacent allocations)
  hipMemsetAsync(cnt, 0, ws_align((size_t)n * 4) + (size_t)n * 4, stream);

  k_cvtW3<<<(256 * 128 + 128 * 256 + 64 * 128 + 255) / 256, 256, 0, stream>>>(
      W1, Wt1h, Wt1l, W2, Wt2h, Wt2l, W3, Wt3h, Wt3l);

  k_hist<<<(E + 255) / 256, 256, 0, stream>>>(etgt, cnt, E);
  k_scan1<<<nb, 256, 0, stream>>>(cnt, row_start, bsum, dinv, n);
  k_scan2<<<1, 256, 0, stream>>>(bsum, bbase, row_start, nb, n);
  k_scan3<<<nb, 256, 0, stream>>>(row_start, bbase, n);
  k_scatter<<<(E + 255) / 256, 256, 0, stream>>>(esrc, etgt, row_start, cursor, csr_src, E);

  // layer 1
  int total2 = n * IN / 2;
  k_scale16<<<(total2 + 255) / 256, 256, 0, stream>>>(x, dinv, xs16, total2);
  k_agg_x<<<(n + 3) / 4, 256, 0, stream>>>(xs16, dinv, row_start, csr_src,
                                           (uint32_t*)A1, mask1, dk1_0, dk1_1, n);
  k_mfma<2, 128><<<grpRB * 8 * 4, 256, 32768, stream>>>(A1, Wt1h, Wt1l, b1, nullptr,
                                                        h1_16, mask1, n, H2, 4, Mb128);

  // layer 2
  k_mfma<0, 256><<<grpRB * 8 * 2, 256, 65536, stream>>>(h1_16, Wt2h, Wt2l, dinv, nullptr,
                                                        hw2_16, nullptr, n, HID, 2, Mb128);
  k_agg_w<<<(n + 3) / 4, 256, 0, stream>>>(hw2_16, dinv, b2, row_start, csr_src,
                                           (uint32_t*)A1, dk2_0, dk2_1, n);

  // layer 3
  k_mfma<1, 128><<<grpRB * 8, 256, 32768, stream>>>(A1, Wt3h, Wt3l, b3, (float*)d_out,
                                                    nullptr, nullptr, n, OD, 1, Mb128);
}